// Round 10
// baseline (232.139 us; speedup 1.0000x reference)
//
#include <hip/hip_runtime.h>

// CTC forward loss, B=256, T=1024, C=128, L=64, S=2L+1=129, BLANK=127.
// One wave per batch element (256 blocks x 64 threads).
//
// Round-9 memory path: NO LDS. Each lane needs exactly one emission column
// (its label, fixed for the whole sequence) plus the wave-uniform BLANK
// column. Per 32-step chunk:
//   - 32 global_load_dword gathers: vNext[j] = row(t0+j)[lab]   (per-lane)
//   - 1  global_load_dword:  lane k<32 holds row(t0+k)[BLANK]; step k
//     broadcasts it with v_readlane at a compile-time index -> SGPR operand.
// All 33 loads are issued at the top of the chunk and consumed one chunk
// later (register double-buffer), so there is exactly one vmcnt drain per
// 32 steps and ~1700 cycles of compute cover the ~900-cycle HBM latency.
// This removes round-8's per-step ds_read pair (label gather was a ~4-way
// bank-conflict read) and all staging instructions.
//
// DP math (verified absmax 0.0 in rounds 6-8): linear-domain recursion
//   a'[s] = (a[s] + a[s-1] + can_skip*a[s-2]) * (p[s]+eps)
// on f32 mantissas with a per-lane int exponent e (true alpha = m * 2^e),
// renormalized every 4 steps (shrink >= pmin^4 ~ 2^-93 > denormal floor,
// growth <= 6^4: no overflow). Lane i owns states 2i+1 (label, aO) and
// 2i+2 (blank, aE); state 0 is a wave-uniform chain (a0, e0). Neighbor
// alignment via v_ldexp(m_{i-1}, e_{i-1}-e_i); dead lanes adopt the
// neighbor's exponent so the advancing front is never flushed; ldexp(0,n)=0
// keeps lane-0 wraparound garbage out of live arithmetic.

#define B_     256
#define T_     1024
#define C_     128
#define L_     64
#define BLANK_ 127
#define EPS_   1e-7f
#define LN2_   0.69314718055994530942f
#define CH     32      // steps per chunk

__device__ __forceinline__ float flog2(float x) { return __builtin_amdgcn_logf(x); }

template <int CTRL>
__device__ __forceinline__ int dpp_i(int x) {
    return __builtin_amdgcn_update_dpp(x, x, CTRL, 0xF, 0xF, false);
}
// whole-wave rotate: lane i receives lane (i-1)&63
__device__ __forceinline__ float ror1_f(float x) {
    return __int_as_float(dpp_i<0x13C>(__float_as_int(x)));
}
__device__ __forceinline__ int ror1_i(int x) { return dpp_i<0x13C>(x); }

__device__ __forceinline__ float fldexp(float x, int n) {
#if __has_builtin(__builtin_amdgcn_ldexpf)
    return __builtin_amdgcn_ldexpf(x, n);
#else
    return ldexpf(x, n);
#endif
}
// frexp-style exponent; 0 for x==0
__device__ __forceinline__ int fexp_of(float x) {
#if __has_builtin(__builtin_amdgcn_frexp_expf)
    return __builtin_amdgcn_frexp_expf(x);
#else
    const int bx = (__float_as_int(x) >> 23) & 0xFF;
    return (x > 0.0f) ? (bx - 126) : 0;
#endif
}
// wave-uniform broadcast of lane K's value (K compile-time) -> SGPR
template <int K>
__device__ __forceinline__ float rdlane(float v) {
    return __int_as_float(__builtin_amdgcn_readlane(__float_as_int(v), K));
}

// One DP step (~22 VALU, no transcendentals).
#define LSTEP(pL, pB)                                                         \
    {                                                                         \
        const float pBe = (pB) + EPS_;                                        \
        const float pLe = (pL) + EPS_;                                        \
        const int   ep  = ror1_i(e);                                          \
        const float mpE = ror1_f(aE);                                         \
        const float mpO = ror1_f(aO);                                         \
        const bool dead = (fmaxf(aE, aO) == 0.0f);                            \
        e = dead ? ep : e;               /* dead lanes track the front */     \
        const int   d   = ep - e;        /* == 0 when mass first arrives */   \
        float prevE = fldexp(mpE, d);                                         \
        const float prevO = fldexp(mpO, d);                                   \
        prevE = isL0 ? fldexp(a0, e0 - e) : prevE;                            \
        const float sk = can_skip ? prevO : 0.0f;                             \
        const float nE = (aE + aO) * pBe;                                     \
        const float nO = (aO + prevE + sk) * pLe;                             \
        a0 *= pBe;                                                            \
        aE = nE; aO = nO;                                                     \
    }

// Renorm every 4 steps. frexp_exp(0)=0 so dead lanes are a no-op.
#define RENORM4                                                               \
    {                                                                         \
        const int x = fexp_of(fmaxf(aE, aO));                                 \
        aE = fldexp(aE, -x); aO = fldexp(aO, -x); e += x;                     \
        const int x0 = fexp_of(a0);                                           \
        a0 = fldexp(a0, -x0); e0 += x0;                                       \
    }

// One full chunk body: 32 steps consuming vL[0..31] / vB lanes 0..31.
#define STEP_K(k)                                                             \
    {                                                                         \
        const float pB = rdlane<k>(vB);                                       \
        LSTEP(vL[k], pB)                                                      \
        if (((k) & 3) == 3) RENORM4                                           \
    }

__global__ __launch_bounds__(64, 1)
void ctc_fwd(const int* __restrict__ yt, const float* __restrict__ yp,
             float* __restrict__ out) {
    const int b    = blockIdx.x;
    const int lane = threadIdx.x;                 // 0..63
    const int lab  = yt[b * L_ + lane];           // label of state 2*lane+1
    const int labp = __shfl_up(lab, 1);           // init-only, off hot path
    const bool can_skip = (lane > 0) && (lab != labp);
    const bool isL0     = (lane == 0);

    const float* __restrict__ base = yp + (size_t)b * T_ * C_;

    // ---- preload chunk 0 (t = 1..32) ----
    float vL[CH], vB;
    {
        const float* src = base + C_;
#pragma unroll
        for (int j = 0; j < CH; ++j) vL[j] = src[(size_t)j * C_ + lab];
        vB = src[(size_t)(lane & 31) * C_ + BLANK_];
    }

    // ---- t=0 init (linear, exponent 0): only states 0 and 1 reachable ----
    float a0 = base[BLANK_] + EPS_;               // state 0 (uniform)
    float aO = isL0 ? (base[lab] + EPS_) : 0.0f;  // state 2i+1
    float aE = 0.0f;                              // state 2i+2
    int   e  = 0, e0 = 0;

    // ---- 31 full chunks: chunk c covers t = 1+32c .. 32+32c (t <= 992) ----
#pragma unroll 1
    for (int c = 0; c < 31; ++c) {
        // issue next chunk's 33 loads (chunk 31 is partial: clamp row 31)
        float nL[CH], nB;
        {
            const float* nsrc = base + (size_t)(33 + 32 * c) * C_;
            const int last = (c == 30) ? 30 : 31;   // max valid row offset
#pragma unroll
            for (int j = 0; j < CH; ++j) {
                const int jj = (j <= last) ? j : last;
                nL[j] = nsrc[(size_t)jj * C_ + lab];
            }
            int r = lane & 31; r = (r <= last) ? r : last;
            nB = nsrc[(size_t)r * C_ + BLANK_];
        }
        // 32 DP steps on the current chunk (no vmem in here)
        STEP_K(0)  STEP_K(1)  STEP_K(2)  STEP_K(3)
        STEP_K(4)  STEP_K(5)  STEP_K(6)  STEP_K(7)
        STEP_K(8)  STEP_K(9)  STEP_K(10) STEP_K(11)
        STEP_K(12) STEP_K(13) STEP_K(14) STEP_K(15)
        STEP_K(16) STEP_K(17) STEP_K(18) STEP_K(19)
        STEP_K(20) STEP_K(21) STEP_K(22) STEP_K(23)
        STEP_K(24) STEP_K(25) STEP_K(26) STEP_K(27)
        STEP_K(28) STEP_K(29) STEP_K(30) STEP_K(31)
        // swap register buffers (the one vmcnt drain point per chunk)
#pragma unroll
        for (int j = 0; j < CH; ++j) vL[j] = nL[j];
        vB = nB;
    }

    // ---- final partial chunk: t = 993..1023 (31 steps) ----
    STEP_K(0)  STEP_K(1)  STEP_K(2)  STEP_K(3)
    STEP_K(4)  STEP_K(5)  STEP_K(6)  STEP_K(7)
    STEP_K(8)  STEP_K(9)  STEP_K(10) STEP_K(11)
    STEP_K(12) STEP_K(13) STEP_K(14) STEP_K(15)
    STEP_K(16) STEP_K(17) STEP_K(18) STEP_K(19)
    STEP_K(20) STEP_K(21) STEP_K(22) STEP_K(23)
    STEP_K(24) STEP_K(25) STEP_K(26) STEP_K(27)
    STEP_K(28) STEP_K(29) STEP_K(30)

    // loss = -ln(alpha[127] + alpha[128]); both live in lane 63 at scale 2^e.
    if (lane == 63) {
        const float s = aE + aO;                  // in [2^-70, 8): v_log safe
        out[b] = -(flog2(s) + (float)e) * LN2_;
    }
}

extern "C" void kernel_launch(void* const* d_in, const int* in_sizes, int n_in,
                              void* d_out, int out_size, void* d_ws, size_t ws_size,
                              hipStream_t stream) {
    const int*   y_true = (const int*)d_in[0];
    const float* y_pred = (const float*)d_in[1];
    float*       out    = (float*)d_out;
    ctc_fwd<<<B_, 64, 0, stream>>>(y_true, y_pred, out);
}